// Round 3
// baseline (146.803 us; speedup 1.0000x reference)
//
#include <hip/hip_runtime.h>
#include <hip/hip_bf16.h>

// phi = exp(-d2/(2*ls^2)) = exp2(-S2*d2), S2 = 1/(2*0.3^2*ln2) = 8.014973
// Expanded: exp2(2*S2*(x.c) - S2*|x|^2 - S2*|c|^2)
//   per-center pack a = (K2*cx, K2*cy, K2*cz, -S2*|c|^2), K2 = 2*S2
//   per-lane  PX = -S2*|x|^2   (keeps exponent <= 0 -> no overflow)
#define S2 8.014973f
#define K2 16.029946f
#define NCHUNK 21  // center-chunks per tile; per-task inner loop ~161 iters

typedef float f2 __attribute__((ext_vector_type(2)));

__global__ void rbf_prep_kernel(const float* __restrict__ centers,
                                const float* __restrict__ cu,
                                const float* __restrict__ cv,
                                const float* __restrict__ cw,
                                float4* __restrict__ cpack, int M) {
    int m = blockIdx.x * 256 + threadIdx.x;
    if (m < M) {
        float cx = centers[3 * m + 0];
        float cy = centers[3 * m + 1];
        float cz = centers[3 * m + 2];
        float4 a, b;
        a.x = K2 * cx;
        a.y = K2 * cy;
        a.z = K2 * cz;
        a.w = -S2 * (cx * cx + cy * cy + cz * cz);
        b.x = cu[m];
        b.y = cv[m];
        b.z = cw[m];
        b.w = 0.f;
        cpack[2 * m + 0] = a;
        cpack[2 * m + 1] = b;
    }
}

// Balanced task pool: task = (tile of 128 points) x (chunk of ~161 centers).
// Grid = 2048 blocks x 256 thr = 8192 waves = 32 waves/CU (no LDS, low VGPR)
// -> full occupancy, and grid-stride over 16422 tasks kills the R2 tail
// imbalance (782 blocks / 256 CUs = 3.05 -> 40% measured occupancy).
// Partial sums go to out via fp32 global atomics (~21 contenders/addr).
__global__ __launch_bounds__(256) void rbf_main_kernel(
    const float* __restrict__ x, const float4* __restrict__ cpack,
    float* __restrict__ out, int N, int M, int NT, int per, int ntask) {
    const int tid = threadIdx.x;
    const int lane = tid & 63;
    const int wave0 =
        __builtin_amdgcn_readfirstlane(blockIdx.x * 4 + (tid >> 6));
    const int nwaves = gridDim.x * 4;

    for (int task = wave0; task < ntask; task += nwaves) {
        const int tile = task % NT;    // uniform
        const int chunk = task / NT;   // uniform
        const int p0 = tile * 128 + lane;
        const int p1 = p0 + 64;

        float x00 = 0.f, x01 = 0.f, x02 = 0.f;
        float x10 = 0.f, x11 = 0.f, x12 = 0.f;
        if (p0 < N) {
            x00 = x[3 * p0 + 0];
            x01 = x[3 * p0 + 1];
            x02 = x[3 * p0 + 2];
        }
        if (p1 < N) {
            x10 = x[3 * p1 + 0];
            x11 = x[3 * p1 + 1];
            x12 = x[3 * p1 + 2];
        }

        const f2 X = {x00, x10};
        const f2 Y = {x01, x11};
        const f2 Z = {x02, x12};
        const f2 PX = {-S2 * (x00 * x00 + x01 * x01 + x02 * x02),
                       -S2 * (x10 * x10 + x11 * x11 + x12 * x12)};

        const int jb = chunk * per;
        const int je = min(jb + per, M);

        f2 au = {0.f, 0.f}, av = {0.f, 0.f}, aw = {0.f, 0.f};

#pragma unroll 4
        for (int j = jb; j < je; ++j) {
            const float4 a = cpack[2 * j + 0];  // uniform addr -> scalar load
            const float4 b = cpack[2 * j + 1];
            f2 e = PX + a.w;
            e += Z * a.z;
            e += Y * a.y;
            e += X * a.x;
            f2 phi;
            phi.x = __builtin_amdgcn_exp2f(e.x);
            phi.y = __builtin_amdgcn_exp2f(e.y);
            au += phi * b.x;
            av += phi * b.y;
            aw += phi * b.z;
        }

        if (chunk == 0) {  // fold base field x*(1-||x||) into chunk-0 partials
            float g0 = 1.f - sqrtf(x00 * x00 + x01 * x01 + x02 * x02);
            au.x += x00 * g0;
            av.x += x01 * g0;
            aw.x += x02 * g0;
            float g1 = 1.f - sqrtf(x10 * x10 + x11 * x11 + x12 * x12);
            au.y += x10 * g1;
            av.y += x11 * g1;
            aw.y += x12 * g1;
        }

        if (p0 < N) {
            atomicAdd(&out[3 * p0 + 0], au.x);
            atomicAdd(&out[3 * p0 + 1], av.x);
            atomicAdd(&out[3 * p0 + 2], aw.x);
        }
        if (p1 < N) {
            atomicAdd(&out[3 * p1 + 0], au.y);
            atomicAdd(&out[3 * p1 + 1], av.y);
            atomicAdd(&out[3 * p1 + 2], aw.y);
        }
    }
}

extern "C" void kernel_launch(void* const* d_in, const int* in_sizes, int n_in,
                              void* d_out, int out_size, void* d_ws,
                              size_t ws_size, hipStream_t stream) {
    const float* x = (const float*)d_in[0];
    const float* centers = (const float*)d_in[1];
    const float* cu = (const float*)d_in[2];
    const float* cv = (const float*)d_in[3];
    const float* cw = (const float*)d_in[4];
    const int N = in_sizes[0] / 3;
    const int M = in_sizes[1] / 3;
    float4* cpack = (float4*)d_ws;
    float* out = (float*)d_out;

    const int NT = (N + 127) / 128;
    const int per = (M + NCHUNK - 1) / NCHUNK;
    const int ntask = NT * NCHUNK;

    hipLaunchKernelGGL(rbf_prep_kernel, dim3((M + 255) / 256), dim3(256), 0,
                       stream, centers, cu, cv, cw, cpack, M);
    hipMemsetAsync(d_out, 0, (size_t)out_size * sizeof(float), stream);
    hipLaunchKernelGGL(rbf_main_kernel, dim3(2048), dim3(256), 0, stream, x,
                       cpack, out, N, M, NT, per, ntask);
}